// Round 1
// baseline (270.925 us; speedup 1.0000x reference)
//
#include <hip/hip_runtime.h>
#include <math.h>

// MultiheadSelfAttention2D: C=256, AC=64, HEADS=16, HEAD_DIM=4, L=4096.
// Transposed attention: out[d,i] = sum_j exp(q_j.k_i) * (V[d,j]/Z_j),
// Z_j = sum_m exp(q_j.k_m). q,k L2-normalized over d=4 -> scores in [-1,1],
// no max-subtraction needed. Q pre-scaled by log2(e) so inner loops use exp2.

constexpr int SL = 4096;     // sequence length (64*64)
constexpr int NH = 16;       // heads
#define LOG2E 1.44269504088896f

__device__ __forceinline__ float fexp2(float x) { return __builtin_amdgcn_exp2f(x); }

// ---------------------------------------------------------------------------
// Kernel 1: QKV projection (1x1 conv == channel matmul) + L2-norm of Q,K.
// Writes Qd [16][4][SL] (per-lane layout), Q4 [16][SL][4] (uniform layout),
// Kd, K4 likewise, V4 [16][SL][4]. Q scaled by log2e.
// Grid: (64 l-tiles, 4 a-blocks), block 256. Wave w handles 12 output rows.
// ---------------------------------------------------------------------------
__global__ __launch_bounds__(256) void qkv_kernel(
    const float* __restrict__ X,
    const float* __restrict__ Wq, const float* __restrict__ bq,
    const float* __restrict__ Wk, const float* __restrict__ bk,
    const float* __restrict__ Wv, const float* __restrict__ bv,
    float* __restrict__ Qd, float* __restrict__ Q4,
    float* __restrict__ Kd, float* __restrict__ K4,
    float* __restrict__ V4)
{
    __shared__ float XL[256 * 64];          // X tile: 256 channels x 64 positions
    const int tid = threadIdx.x;
    const int lt  = blockIdx.x;             // l-tile (64 tiles of 64)
    const int ab  = blockIdx.y;             // a-block (4 blocks of 48 rows)

    // stage X[:, lt*64 .. lt*64+63] into LDS (float4 along l)
    const float4* Xg  = (const float4*)X;
    float4*       XL4 = (float4*)XL;
    #pragma unroll
    for (int i = 0; i < 16; ++i) {
        int idx = tid + i * 256;            // 0..4095
        int c = idx >> 4, lq = idx & 15;
        XL4[c * 16 + lq] = Xg[c * (SL / 4) + lt * 16 + lq];
    }
    __syncthreads();

    const int lane   = tid & 63;
    const int wv     = __builtin_amdgcn_readfirstlane(tid >> 6);
    const int a_base = ab * 48 + wv * 12;   // 12 rows per wave, covers a in [0,192)
    const int l      = lt * 64 + lane;

    float acc[12];
    const float* wrow[12];
    #pragma unroll
    for (int k = 0; k < 12; ++k) {
        int a = a_base + k;
        if (a < 64)       { wrow[k] = Wq + a * 256;         acc[k] = bq[a]; }
        else if (a < 128) { wrow[k] = Wk + (a - 64) * 256;  acc[k] = bk[a - 64]; }
        else              { wrow[k] = Wv + (a - 128) * 256; acc[k] = bv[a - 128]; }
    }

    #pragma unroll 4
    for (int c = 0; c < 256; ++c) {
        float x = XL[c * 64 + lane];
        #pragma unroll
        for (int k = 0; k < 12; ++k) acc[k] = fmaf(wrow[k][c], x, acc[k]);
    }

    // groups of 4 rows = one (type, head): normalize Q/K, write layouts
    #pragma unroll
    for (int g = 0; g < 3; ++g) {
        int a0 = a_base + g * 4;
        float y0 = acc[g * 4 + 0], y1 = acc[g * 4 + 1];
        float y2 = acc[g * 4 + 2], y3 = acc[g * 4 + 3];
        int type = a0 >> 6;                 // 0=Q 1=K 2=V (wave-uniform)
        if (type < 2) {
            float n   = sqrtf(y0 * y0 + y1 * y1 + y2 * y2 + y3 * y3);
            float inv = 1.0f / fmaxf(n, 1e-12f);
            if (type == 0) inv *= LOG2E;    // fold log2(e) into Q once
            y0 *= inv; y1 *= inv; y2 *= inv; y3 *= inv;
        }
        int h = (a0 & 63) >> 2;             // head index within its type
        if (type == 0) {
            Qd[(h * 4 + 0) * SL + l] = y0;
            Qd[(h * 4 + 1) * SL + l] = y1;
            Qd[(h * 4 + 2) * SL + l] = y2;
            Qd[(h * 4 + 3) * SL + l] = y3;
            ((float4*)Q4)[h * SL + l] = make_float4(y0, y1, y2, y3);
        } else if (type == 1) {
            Kd[(h * 4 + 0) * SL + l] = y0;
            Kd[(h * 4 + 1) * SL + l] = y1;
            Kd[(h * 4 + 2) * SL + l] = y2;
            Kd[(h * 4 + 3) * SL + l] = y3;
            ((float4*)K4)[h * SL + l] = make_float4(y0, y1, y2, y3);
        } else {
            ((float4*)V4)[h * SL + l] = make_float4(y0, y1, y2, y3);
        }
    }
}

// ---------------------------------------------------------------------------
// Kernel 2: partial Z. Zp[mc][h*SL+j] = sum over m-chunk of exp2(q_j.k_m).
// Grid (16 j-tiles, 16 heads, 4 m-chunks), block 256. k_m is wave-uniform
// (s_load), q_j per-lane.
// ---------------------------------------------------------------------------
__global__ __launch_bounds__(256) void zpart_kernel(
    const float* __restrict__ Qd, const float* __restrict__ K4,
    float* __restrict__ Zp)
{
    const int j  = blockIdx.x * 256 + threadIdx.x;
    const int h  = blockIdx.y;
    const int mc = blockIdx.z;

    const float q0 = Qd[(h * 4 + 0) * SL + j];
    const float q1 = Qd[(h * 4 + 1) * SL + j];
    const float q2 = Qd[(h * 4 + 2) * SL + j];
    const float q3 = Qd[(h * 4 + 3) * SL + j];

    const float4* Kh = ((const float4*)K4) + h * SL + mc * 1024;
    float z0 = 0.f, z1 = 0.f, z2 = 0.f, z3 = 0.f;
    #pragma unroll 2
    for (int m = 0; m < 1024; m += 4) {
        float4 ka = Kh[m + 0], kb = Kh[m + 1], kc = Kh[m + 2], kd = Kh[m + 3];
        z0 += fexp2(fmaf(q0, ka.x, fmaf(q1, ka.y, fmaf(q2, ka.z, q3 * ka.w))));
        z1 += fexp2(fmaf(q0, kb.x, fmaf(q1, kb.y, fmaf(q2, kb.z, q3 * kb.w))));
        z2 += fexp2(fmaf(q0, kc.x, fmaf(q1, kc.y, fmaf(q2, kc.z, q3 * kc.w))));
        z3 += fexp2(fmaf(q0, kd.x, fmaf(q1, kd.y, fmaf(q2, kd.z, q3 * kd.w))));
    }
    Zp[(mc * NH + h) * SL + j] = (z0 + z1) + (z2 + z3);
}

// ---------------------------------------------------------------------------
// Kernel 2b: Z = sum of 4 partials; Vp4 = V4 / Z. Grid 256 blocks x 256.
// ---------------------------------------------------------------------------
__global__ __launch_bounds__(256) void scalev_kernel(
    const float* __restrict__ Zp, const float* __restrict__ V4,
    float* __restrict__ Vp4)
{
    int idx = blockIdx.x * 256 + threadIdx.x;   // h*SL + j, 0..65535
    float z = (Zp[idx] + Zp[65536 + idx]) + (Zp[131072 + idx] + Zp[196608 + idx]);
    float inv = 1.0f / z;                       // z >= 4096/e, never 0
    float4 v = ((const float4*)V4)[idx];
    ((float4*)Vp4)[idx] = make_float4(v.x * inv, v.y * inv, v.z * inv, v.w * inv);
}

// ---------------------------------------------------------------------------
// Kernel 3: output pass. AO[h*4+d][i] += sum over j-chunk of
// exp2(q_j.k_i) * Vp[d,j]. k_i per-lane, q_j/vp_j wave-uniform.
// Grid (16 i-tiles, 16 heads, 4 j-chunks), block 256.
// ---------------------------------------------------------------------------
__global__ __launch_bounds__(256) void opart_kernel(
    const float* __restrict__ Kd, const float* __restrict__ Q4,
    const float* __restrict__ Vp4, float* __restrict__ AO)
{
    const int i  = blockIdx.x * 256 + threadIdx.x;
    const int h  = blockIdx.y;
    const int jc = blockIdx.z;

    const float k0 = Kd[(h * 4 + 0) * SL + i];
    const float k1 = Kd[(h * 4 + 1) * SL + i];
    const float k2 = Kd[(h * 4 + 2) * SL + i];
    const float k3 = Kd[(h * 4 + 3) * SL + i];

    const float4* Qh = ((const float4*)Q4)  + h * SL + jc * 1024;
    const float4* Vh = ((const float4*)Vp4) + h * SL + jc * 1024;

    float a0 = 0.f, a1 = 0.f, a2 = 0.f, a3 = 0.f;
    #pragma unroll 2
    for (int j = 0; j < 1024; j += 2) {
        float4 qa = Qh[j + 0]; float4 va = Vh[j + 0];
        float4 qb = Qh[j + 1]; float4 vb = Vh[j + 1];
        float ea = fexp2(fmaf(k0, qa.x, fmaf(k1, qa.y, fmaf(k2, qa.z, k3 * qa.w))));
        float eb = fexp2(fmaf(k0, qb.x, fmaf(k1, qb.y, fmaf(k2, qb.z, k3 * qb.w))));
        a0 = fmaf(ea, va.x, a0); a1 = fmaf(ea, va.y, a1);
        a2 = fmaf(ea, va.z, a2); a3 = fmaf(ea, va.w, a3);
        a0 = fmaf(eb, vb.x, a0); a1 = fmaf(eb, vb.y, a1);
        a2 = fmaf(eb, vb.z, a2); a3 = fmaf(eb, vb.w, a3);
    }
    unsafeAtomicAdd(&AO[(h * 4 + 0) * SL + i], a0);
    unsafeAtomicAdd(&AO[(h * 4 + 1) * SL + i], a1);
    unsafeAtomicAdd(&AO[(h * 4 + 2) * SL + i], a2);
    unsafeAtomicAdd(&AO[(h * 4 + 3) * SL + i], a3);
}

// ---------------------------------------------------------------------------
// Kernel 4: output projection + bias + residual.
// Y[c][l] = bo[c] + X[c][l] + sum_o Wo[c][o]*AO[o][l].
// Grid (64 l-tiles, 16 c-blocks), block 256; wave handles 4 channels.
// ---------------------------------------------------------------------------
__global__ __launch_bounds__(256) void oproj_kernel(
    const float* __restrict__ AO, const float* __restrict__ Wo,
    const float* __restrict__ bo, const float* __restrict__ X,
    float* __restrict__ Y)
{
    const int lane = threadIdx.x & 63;
    const int wv   = __builtin_amdgcn_readfirstlane(threadIdx.x >> 6);
    const int l    = blockIdx.x * 64 + lane;
    const int cb   = blockIdx.y * 16 + wv * 4;

    float a0 = bo[cb + 0], a1 = bo[cb + 1], a2 = bo[cb + 2], a3 = bo[cb + 3];
    #pragma unroll 8
    for (int o = 0; o < 64; ++o) {
        float x = AO[o * SL + l];
        a0 = fmaf(Wo[(cb + 0) * 64 + o], x, a0);
        a1 = fmaf(Wo[(cb + 1) * 64 + o], x, a1);
        a2 = fmaf(Wo[(cb + 2) * 64 + o], x, a2);
        a3 = fmaf(Wo[(cb + 3) * 64 + o], x, a3);
    }
    Y[(cb + 0) * SL + l] = a0 + X[(cb + 0) * SL + l];
    Y[(cb + 1) * SL + l] = a1 + X[(cb + 1) * SL + l];
    Y[(cb + 2) * SL + l] = a2 + X[(cb + 2) * SL + l];
    Y[(cb + 3) * SL + l] = a3 + X[(cb + 3) * SL + l];
}

// ---------------------------------------------------------------------------
extern "C" void kernel_launch(void* const* d_in, const int* in_sizes, int n_in,
                              void* d_out, int out_size, void* d_ws, size_t ws_size,
                              hipStream_t stream)
{
    const float* X  = (const float*)d_in[0];
    const float* Wq = (const float*)d_in[1];
    const float* bq = (const float*)d_in[2];
    const float* Wk = (const float*)d_in[3];
    const float* bk = (const float*)d_in[4];
    const float* Wv = (const float*)d_in[5];
    const float* bv = (const float*)d_in[6];
    const float* Wo = (const float*)d_in[7];
    const float* bo = (const float*)d_in[8];
    float* Y = (float*)d_out;

    // workspace layout: 8 buffers x 262144 floats = 8.4 MB
    float* ws  = (float*)d_ws;
    float* Qd  = ws + 0 * 262144;   // [16][4][SL], scaled by log2e
    float* Q4  = ws + 1 * 262144;   // [16][SL][4], scaled by log2e
    float* Kd  = ws + 2 * 262144;   // [16][4][SL]
    float* K4  = ws + 3 * 262144;   // [16][SL][4]
    float* V4  = ws + 4 * 262144;   // [16][SL][4]
    float* Vp4 = ws + 5 * 262144;   // [16][SL][4]  V/Z
    float* Zp  = ws + 6 * 262144;   // [4][16][SL]  partial Z
    float* AO  = ws + 7 * 262144;   // [64][SL]     attention output

    qkv_kernel<<<dim3(64, 4), 256, 0, stream>>>(X, Wq, bq, Wk, bk, Wv, bv,
                                                Qd, Q4, Kd, K4, V4);
    zpart_kernel<<<dim3(16, 16, 4), 256, 0, stream>>>(Qd, K4, Zp);
    scalev_kernel<<<256, 256, 0, stream>>>(Zp, V4, Vp4);
    hipMemsetAsync(AO, 0, 262144 * sizeof(float), stream);
    opart_kernel<<<dim3(16, 16, 4), 256, 0, stream>>>(Kd, Q4, Vp4, AO);
    oproj_kernel<<<dim3(64, 16), 256, 0, stream>>>(AO, Wo, bo, X, Y);
}

// Round 2
// 240.019 us; speedup vs baseline: 1.1288x; 1.1288x over previous
//
#include <hip/hip_runtime.h>
#include <math.h>

// MultiheadSelfAttention2D: C=256, AC=64, HEADS=16, HEAD_DIM=4, L=4096.
// Transposed attention: out[d,i] = sum_j exp(q_j.k_i) * (V[d,j]/Z_j),
// Z_j = sum_m exp(q_j.k_m). q,k L2-normalized over d=4 -> scores in [-1,1],
// no max-subtraction needed. Q pre-scaled by log2(e) so inner loops use exp2.
//
// R2: latency-hiding round. zpart/opart were latency-bound (VALUBusy 54%,
// occupancy 37%): 8 chunks (full occupancy) + 8-deep batched scalar loads
// (16 s_loads in flight) + single interleaved QV stream for opart.

constexpr int SL = 4096;     // sequence length (64*64)
constexpr int NH = 16;       // heads
#define LOG2E 1.44269504088896f

__device__ __forceinline__ float fexp2(float x) { return __builtin_amdgcn_exp2f(x); }

// ---------------------------------------------------------------------------
// Kernel 1: QKV projection (1x1 conv == channel matmul) + L2-norm of Q,K.
// Writes Qd [16][4][SL] (per-lane layout, log2e-scaled), QV8[h][l][0..3]=q
// (log2e-scaled), Kd [16][4][SL], K4 [16][SL][4], V4 [16][SL][4].
// Grid: (64 l-tiles, 4 a-blocks), block 256. Wave w handles 12 output rows.
// ---------------------------------------------------------------------------
__global__ __launch_bounds__(256) void qkv_kernel(
    const float* __restrict__ X,
    const float* __restrict__ Wq, const float* __restrict__ bq,
    const float* __restrict__ Wk, const float* __restrict__ bk,
    const float* __restrict__ Wv, const float* __restrict__ bv,
    float* __restrict__ Qd, float* __restrict__ QV8,
    float* __restrict__ Kd, float* __restrict__ K4,
    float* __restrict__ V4)
{
    __shared__ float XL[256 * 64];          // X tile: 256 channels x 64 positions
    const int tid = threadIdx.x;
    const int lt  = blockIdx.x;             // l-tile (64 tiles of 64)
    const int ab  = blockIdx.y;             // a-block (4 blocks of 48 rows)

    // stage X[:, lt*64 .. lt*64+63] into LDS (float4 along l)
    const float4* Xg  = (const float4*)X;
    float4*       XL4 = (float4*)XL;
    #pragma unroll
    for (int i = 0; i < 16; ++i) {
        int idx = tid + i * 256;            // 0..4095
        int c = idx >> 4, lq = idx & 15;
        XL4[c * 16 + lq] = Xg[c * (SL / 4) + lt * 16 + lq];
    }
    __syncthreads();

    const int lane   = tid & 63;
    const int wv     = __builtin_amdgcn_readfirstlane(tid >> 6);
    const int a_base = ab * 48 + wv * 12;   // 12 rows per wave, covers a in [0,192)
    const int l      = lt * 64 + lane;

    float acc[12];
    const float* wrow[12];
    #pragma unroll
    for (int k = 0; k < 12; ++k) {
        int a = a_base + k;
        if (a < 64)       { wrow[k] = Wq + a * 256;         acc[k] = bq[a]; }
        else if (a < 128) { wrow[k] = Wk + (a - 64) * 256;  acc[k] = bk[a - 64]; }
        else              { wrow[k] = Wv + (a - 128) * 256; acc[k] = bv[a - 128]; }
    }

    #pragma unroll 4
    for (int c = 0; c < 256; ++c) {
        float x = XL[c * 64 + lane];
        #pragma unroll
        for (int k = 0; k < 12; ++k) acc[k] = fmaf(wrow[k][c], x, acc[k]);
    }

    // groups of 4 rows = one (type, head): normalize Q/K, write layouts
    #pragma unroll
    for (int g = 0; g < 3; ++g) {
        int a0 = a_base + g * 4;
        float y0 = acc[g * 4 + 0], y1 = acc[g * 4 + 1];
        float y2 = acc[g * 4 + 2], y3 = acc[g * 4 + 3];
        int type = a0 >> 6;                 // 0=Q 1=K 2=V (wave-uniform)
        if (type < 2) {
            float n   = sqrtf(y0 * y0 + y1 * y1 + y2 * y2 + y3 * y3);
            float inv = 1.0f / fmaxf(n, 1e-12f);
            if (type == 0) inv *= LOG2E;    // fold log2(e) into Q once
            y0 *= inv; y1 *= inv; y2 *= inv; y3 *= inv;
        }
        int h = (a0 & 63) >> 2;             // head index within its type
        if (type == 0) {
            Qd[(h * 4 + 0) * SL + l] = y0;
            Qd[(h * 4 + 1) * SL + l] = y1;
            Qd[(h * 4 + 2) * SL + l] = y2;
            Qd[(h * 4 + 3) * SL + l] = y3;
            ((float4*)QV8)[(h * SL + l) * 2] = make_float4(y0, y1, y2, y3);
        } else if (type == 1) {
            Kd[(h * 4 + 0) * SL + l] = y0;
            Kd[(h * 4 + 1) * SL + l] = y1;
            Kd[(h * 4 + 2) * SL + l] = y2;
            Kd[(h * 4 + 3) * SL + l] = y3;
            ((float4*)K4)[h * SL + l] = make_float4(y0, y1, y2, y3);
        } else {
            ((float4*)V4)[h * SL + l] = make_float4(y0, y1, y2, y3);
        }
    }
}

// ---------------------------------------------------------------------------
// Kernel 2: partial Z. Zp[mc][h*SL+j] = sum over m-chunk (512) of
// exp2(q_j.k_m). Grid (16 j-tiles, 16 heads, 8 m-chunks), block 256.
// k_m wave-uniform (s_load batch of 8), q_j per-lane.
// ---------------------------------------------------------------------------
__global__ __launch_bounds__(256) void zpart_kernel(
    const float* __restrict__ Qd, const float* __restrict__ K4,
    float* __restrict__ Zp)
{
    const int j  = blockIdx.x * 256 + threadIdx.x;
    const int h  = blockIdx.y;
    const int mc = blockIdx.z;              // 8 chunks of 512

    const float q0 = Qd[(h * 4 + 0) * SL + j];
    const float q1 = Qd[(h * 4 + 1) * SL + j];
    const float q2 = Qd[(h * 4 + 2) * SL + j];
    const float q3 = Qd[(h * 4 + 3) * SL + j];

    const float4* Kh = ((const float4*)K4) + h * SL + mc * 512;
    float z0 = 0.f, z1 = 0.f, z2 = 0.f, z3 = 0.f;
    for (int m = 0; m < 512; m += 8) {
        float4 t[8];
        #pragma unroll
        for (int u = 0; u < 8; ++u) t[u] = Kh[m + u];
        #pragma unroll
        for (int u = 0; u < 8; ++u) {
            float4 k = t[u];
            float e = fexp2(fmaf(q0, k.x, fmaf(q1, k.y, fmaf(q2, k.z, q3 * k.w))));
            if      ((u & 3) == 0) z0 += e;
            else if ((u & 3) == 1) z1 += e;
            else if ((u & 3) == 2) z2 += e;
            else                   z3 += e;
        }
    }
    Zp[(mc * NH + h) * SL + j] = (z0 + z1) + (z2 + z3);
}

// ---------------------------------------------------------------------------
// Kernel 2b: Z = sum of 8 partials; QV8[h][j][4..7] = V/Z. Grid 256 x 256.
// ---------------------------------------------------------------------------
__global__ __launch_bounds__(256) void scalev_kernel(
    const float* __restrict__ Zp, const float* __restrict__ V4,
    float* __restrict__ QV8)
{
    int idx = blockIdx.x * 256 + threadIdx.x;   // h*SL + j, 0..65535
    float z = 0.f;
    #pragma unroll
    for (int p = 0; p < 8; ++p) z += Zp[p * 65536 + idx];
    float inv = 1.0f / z;                       // z >= 4096/e, never 0
    float4 v = ((const float4*)V4)[idx];
    ((float4*)QV8)[idx * 2 + 1] = make_float4(v.x * inv, v.y * inv, v.z * inv, v.w * inv);
}

// ---------------------------------------------------------------------------
// Kernel 3: output pass. AO[h*4+d][i] += sum over j-chunk (512) of
// exp2(q_j.k_i) * Vp[d,j]. k_i per-lane; {q_j, vp_j} one interleaved
// wave-uniform 32B stream (s_load batch of 8 j's = 64 scalars).
// Grid (16 i-tiles, 16 heads, 8 j-chunks), block 256.
// ---------------------------------------------------------------------------
__global__ __launch_bounds__(256) void opart_kernel(
    const float* __restrict__ Kd, const float* __restrict__ QV8,
    float* __restrict__ AO)
{
    const int i  = blockIdx.x * 256 + threadIdx.x;
    const int h  = blockIdx.y;
    const int jc = blockIdx.z;              // 8 chunks of 512

    const float k0 = Kd[(h * 4 + 0) * SL + i];
    const float k1 = Kd[(h * 4 + 1) * SL + i];
    const float k2 = Kd[(h * 4 + 2) * SL + i];
    const float k3 = Kd[(h * 4 + 3) * SL + i];

    const float4* QV = ((const float4*)QV8) + ((h * SL) + jc * 512) * 2;

    float a0 = 0.f, a1 = 0.f, a2 = 0.f, a3 = 0.f;
    float b0 = 0.f, b1 = 0.f, b2 = 0.f, b3 = 0.f;
    for (int j = 0; j < 512; j += 8) {
        float4 t[16];
        #pragma unroll
        for (int u = 0; u < 16; ++u) t[u] = QV[j * 2 + u];
        #pragma unroll
        for (int u = 0; u < 8; ++u) {
            float4 q = t[2 * u], v = t[2 * u + 1];
            float e = fexp2(fmaf(k0, q.x, fmaf(k1, q.y, fmaf(k2, q.z, k3 * q.w))));
            if (u & 1) {
                b0 = fmaf(e, v.x, b0); b1 = fmaf(e, v.y, b1);
                b2 = fmaf(e, v.z, b2); b3 = fmaf(e, v.w, b3);
            } else {
                a0 = fmaf(e, v.x, a0); a1 = fmaf(e, v.y, a1);
                a2 = fmaf(e, v.z, a2); a3 = fmaf(e, v.w, a3);
            }
        }
    }
    unsafeAtomicAdd(&AO[(h * 4 + 0) * SL + i], a0 + b0);
    unsafeAtomicAdd(&AO[(h * 4 + 1) * SL + i], a1 + b1);
    unsafeAtomicAdd(&AO[(h * 4 + 2) * SL + i], a2 + b2);
    unsafeAtomicAdd(&AO[(h * 4 + 3) * SL + i], a3 + b3);
}

// ---------------------------------------------------------------------------
// Kernel 4: output projection + bias + residual.
// Y[c][l] = bo[c] + X[c][l] + sum_o Wo[c][o]*AO[o][l].
// Grid (64 l-tiles, 16 c-blocks), block 256; wave handles 4 channels.
// ---------------------------------------------------------------------------
__global__ __launch_bounds__(256) void oproj_kernel(
    const float* __restrict__ AO, const float* __restrict__ Wo,
    const float* __restrict__ bo, const float* __restrict__ X,
    float* __restrict__ Y)
{
    const int lane = threadIdx.x & 63;
    const int wv   = __builtin_amdgcn_readfirstlane(threadIdx.x >> 6);
    const int l    = blockIdx.x * 64 + lane;
    const int cb   = blockIdx.y * 16 + wv * 4;

    float a0 = bo[cb + 0], a1 = bo[cb + 1], a2 = bo[cb + 2], a3 = bo[cb + 3];
    #pragma unroll 16
    for (int o = 0; o < 64; ++o) {
        float x = AO[o * SL + l];
        a0 = fmaf(Wo[(cb + 0) * 64 + o], x, a0);
        a1 = fmaf(Wo[(cb + 1) * 64 + o], x, a1);
        a2 = fmaf(Wo[(cb + 2) * 64 + o], x, a2);
        a3 = fmaf(Wo[(cb + 3) * 64 + o], x, a3);
    }
    Y[(cb + 0) * SL + l] = a0 + X[(cb + 0) * SL + l];
    Y[(cb + 1) * SL + l] = a1 + X[(cb + 1) * SL + l];
    Y[(cb + 2) * SL + l] = a2 + X[(cb + 2) * SL + l];
    Y[(cb + 3) * SL + l] = a3 + X[(cb + 3) * SL + l];
}

// ---------------------------------------------------------------------------
extern "C" void kernel_launch(void* const* d_in, const int* in_sizes, int n_in,
                              void* d_out, int out_size, void* d_ws, size_t ws_size,
                              hipStream_t stream)
{
    const float* X  = (const float*)d_in[0];
    const float* Wq = (const float*)d_in[1];
    const float* bq = (const float*)d_in[2];
    const float* Wk = (const float*)d_in[3];
    const float* bk = (const float*)d_in[4];
    const float* Wv = (const float*)d_in[5];
    const float* bv = (const float*)d_in[6];
    const float* Wo = (const float*)d_in[7];
    const float* bo = (const float*)d_in[8];
    float* Y = (float*)d_out;

    // workspace layout: 9.4 MB of floats
    float* ws  = (float*)d_ws;
    float* Qd  = ws;                         // [16][4][SL]      262144
    float* Kd  = Qd  + 262144;               // [16][4][SL]      262144
    float* K4  = Kd  + 262144;               // [16][SL][4]      262144
    float* V4  = K4  + 262144;               // [16][SL][4]      262144
    float* AO  = V4  + 262144;               // [64][SL]         262144
    float* QV8 = AO  + 262144;               // [16][SL][8]      524288
    float* Zp  = QV8 + 524288;               // [8][16][SL]      524288

    qkv_kernel<<<dim3(64, 4), 256, 0, stream>>>(X, Wq, bq, Wk, bk, Wv, bv,
                                                Qd, QV8, Kd, K4, V4);
    zpart_kernel<<<dim3(16, 16, 8), 256, 0, stream>>>(Qd, K4, Zp);
    scalev_kernel<<<256, 256, 0, stream>>>(Zp, V4, QV8);
    hipMemsetAsync(AO, 0, 262144 * sizeof(float), stream);
    opart_kernel<<<dim3(16, 16, 8), 256, 0, stream>>>(Kd, QV8, AO);
    oproj_kernel<<<dim3(64, 16), 256, 0, stream>>>(AO, Wo, bo, X, Y);
}

// Round 4
// 174.790 us; speedup vs baseline: 1.5500x; 1.3732x over previous
//
#include <hip/hip_runtime.h>
#include <math.h>

// MultiheadSelfAttention2D: C=256, AC=64, HEADS=16, HEAD_DIM=4, L=4096.
// out[d,i] = sum_j exp(q_j.k_i) * (V[d,j]/Z_j), Z_j = sum_m exp(q_j.k_m).
// q,k L2-normalized over d=4 -> scores in [-1,1]; Q pre-scaled by log2(e).
//
// R3b: MFMA restructure (R3 + compile fix: cvt_pkrtz returns __fp16 vectors,
// bit_cast to _Float16 vectors for the mfma builtin).
// v_mfma_f32_16x16x16_f16 computes 16x16 score tiles (K-dim = head_dim 4,
// padded with zeros); its C layout (col=lane&15, row=quad*4+reg) EQUALS the
// B-operand layout (n=lane&15, k=quad*4+e), so exp2+cvt_pkrtz feeds the PV
// mfma directly with no cross-lane swizzle. Trans pipe (537M exps) is the
// predicted floor.

constexpr int SL = 4096;
constexpr int NH = 16;
#define LOG2E 1.44269504088896f

typedef _Float16 half4  __attribute__((ext_vector_type(4)));
typedef __fp16   fp16x2 __attribute__((ext_vector_type(2)));
typedef float    f32x4  __attribute__((ext_vector_type(4)));

__device__ __forceinline__ float fexp2(float x) { return __builtin_amdgcn_exp2f(x); }

// ---------------------------------------------------------------------------
// Kernel 1: QKV projection + L2-norm. Writes Qf [16][SL][4] f16 (log2e-
// scaled), Kf [16][SL][4] f16, V4 [16][SL][4] fp32.
// Grid (64 l-tiles, 4 a-blocks), block 256; wave handles 12 output rows.
// ---------------------------------------------------------------------------
__global__ __launch_bounds__(256) void qkv_kernel(
    const float* __restrict__ X,
    const float* __restrict__ Wq, const float* __restrict__ bq,
    const float* __restrict__ Wk, const float* __restrict__ bk,
    const float* __restrict__ Wv, const float* __restrict__ bv,
    _Float16* __restrict__ Qf, _Float16* __restrict__ Kf,
    float* __restrict__ V4)
{
    __shared__ float XL[256 * 64];
    const int tid = threadIdx.x;
    const int lt  = blockIdx.x;
    const int ab  = blockIdx.y;

    const float4* Xg  = (const float4*)X;
    float4*       XL4 = (float4*)XL;
    #pragma unroll
    for (int i = 0; i < 16; ++i) {
        int idx = tid + i * 256;
        int c = idx >> 4, lq = idx & 15;
        XL4[c * 16 + lq] = Xg[c * (SL / 4) + lt * 16 + lq];
    }
    __syncthreads();

    const int lane   = tid & 63;
    const int wv     = __builtin_amdgcn_readfirstlane(tid >> 6);
    const int a_base = ab * 48 + wv * 12;
    const int l      = lt * 64 + lane;

    float acc[12];
    const float* wrow[12];
    #pragma unroll
    for (int k = 0; k < 12; ++k) {
        int a = a_base + k;
        if (a < 64)       { wrow[k] = Wq + a * 256;         acc[k] = bq[a]; }
        else if (a < 128) { wrow[k] = Wk + (a - 64) * 256;  acc[k] = bk[a - 64]; }
        else              { wrow[k] = Wv + (a - 128) * 256; acc[k] = bv[a - 128]; }
    }

    #pragma unroll 4
    for (int c = 0; c < 256; ++c) {
        float x = XL[c * 64 + lane];
        #pragma unroll
        for (int k = 0; k < 12; ++k) acc[k] = fmaf(wrow[k][c], x, acc[k]);
    }

    #pragma unroll
    for (int g = 0; g < 3; ++g) {
        int a0 = a_base + g * 4;
        float y0 = acc[g * 4 + 0], y1 = acc[g * 4 + 1];
        float y2 = acc[g * 4 + 2], y3 = acc[g * 4 + 3];
        int type = a0 >> 6;                 // 0=Q 1=K 2=V
        if (type < 2) {
            float n   = sqrtf(y0 * y0 + y1 * y1 + y2 * y2 + y3 * y3);
            float inv = 1.0f / fmaxf(n, 1e-12f);
            if (type == 0) inv *= LOG2E;
            y0 *= inv; y1 *= inv; y2 *= inv; y3 *= inv;
        }
        int h = (a0 & 63) >> 2;
        if (type == 2) {
            ((float4*)V4)[h * SL + l] = make_float4(y0, y1, y2, y3);
        } else {
            half4 p;
            p[0] = (_Float16)y0; p[1] = (_Float16)y1;
            p[2] = (_Float16)y2; p[3] = (_Float16)y3;
            _Float16* dst = (type == 0) ? Qf : Kf;
            *(half4*)(dst + (size_t)(h * SL + l) * 4) = p;
        }
    }
}

// ---------------------------------------------------------------------------
// Kernel 2: Z-pass (MFMA). Block = (64 j's, head, i-chunk of 2048).
// Wave: j-tile of 16 (B operand, fixed), loops i via LDS-staged K tiles
// (A operand). Scores S[i_local][j]; Z partial = sum of exp2 over rows and
// steps, reduced across quads.
// ---------------------------------------------------------------------------
__global__ __launch_bounds__(256) void zmfma_kernel(
    const _Float16* __restrict__ Qf, const _Float16* __restrict__ Kf,
    float* __restrict__ Zp)
{
    __shared__ _Float16 KL[2048 * 4];     // 16 KB
    const int tid = threadIdx.x;
    const int h   = blockIdx.y;
    const int ic  = blockIdx.z;

    // stage K chunk [2048][4] f16, linear
    {
        const int4* Kg = (const int4*)(Kf + (size_t)(h * SL + ic * 2048) * 4);
        int4* KLv = (int4*)KL;
        #pragma unroll
        for (int u = 0; u < 4; ++u) KLv[tid + u * 256] = Kg[tid + u * 256];
    }
    __syncthreads();

    const int lane = tid & 63;
    const int wv   = __builtin_amdgcn_readfirstlane(tid >> 6);
    const int l16  = lane & 15;
    const int jb   = blockIdx.x * 64 + wv * 16;

    // B operand: Q j-tile. quad0 holds k=0..3 (the 4 q comps); quads 1-3 zero.
    half4 bq = (half4)(_Float16)0.f;
    if (lane < 16) bq = *(const half4*)(Qf + (size_t)(h * SL + jb + lane) * 4);

    const half4* KA = (const half4*)KL;   // A tiles: index t*16 + l16
    const f32x4 cz = {0.f, 0.f, 0.f, 0.f};
    f32x4 zacc = cz;

    #pragma unroll 8
    for (int t = 0; t < 128; ++t) {
        half4 ak = KA[t * 16 + l16];      // A[m=i][k=d]; quads1-3 k>=4 vs B=0
        f32x4 s = __builtin_amdgcn_mfma_f32_16x16x16f16(ak, bq, cz, 0, 0, 0);
        zacc[0] += fexp2(s[0]);
        zacc[1] += fexp2(s[1]);
        zacc[2] += fexp2(s[2]);
        zacc[3] += fexp2(s[3]);
    }
    float z = (zacc[0] + zacc[1]) + (zacc[2] + zacc[3]);
    z += __shfl_xor(z, 16);
    z += __shfl_xor(z, 32);
    if (lane < 16) Zp[(ic * NH + h) * SL + jb + lane] = z;
}

// ---------------------------------------------------------------------------
// Kernel 2b: Z = Zp0+Zp1; VpT[h][d][j] = f16(V[h][j][d]/Z). Grid 256x256.
// ---------------------------------------------------------------------------
__global__ __launch_bounds__(256) void scalev_kernel(
    const float* __restrict__ Zp, const float* __restrict__ V4,
    _Float16* __restrict__ Vp)
{
    int idx = blockIdx.x * 256 + threadIdx.x;   // h*SL + j
    int h = idx >> 12, j = idx & 4095;
    float z = Zp[idx] + Zp[65536 + idx];
    float inv = 1.0f / z;
    float4 v = ((const float4*)V4)[idx];
    Vp[(size_t)(h * 4 + 0) * SL + j] = (_Float16)(v.x * inv);
    Vp[(size_t)(h * 4 + 1) * SL + j] = (_Float16)(v.y * inv);
    Vp[(size_t)(h * 4 + 2) * SL + j] = (_Float16)(v.z * inv);
    Vp[(size_t)(h * 4 + 3) * SL + j] = (_Float16)(v.w * inv);
}

// ---------------------------------------------------------------------------
// Kernel 3: output pass (MFMA). Block = (64 i's, head, j-chunk of 1024).
// Wave: i-tile of 16 (B=K fixed). Per 16-j step: score mfma (A=Q from LDS),
// exp2 x4, cvt_pkrtz pack -> E tile is directly the B operand of the PV
// mfma (A = Vp[d][j] from LDS, rows 4-15 garbage/ignored).
// ---------------------------------------------------------------------------
__global__ __launch_bounds__(256) void omfma_kernel(
    const _Float16* __restrict__ Qf, const _Float16* __restrict__ Kf,
    const _Float16* __restrict__ Vp, float* __restrict__ AO)
{
    __shared__ _Float16 QL[1024 * 4];     // 8 KB
    __shared__ _Float16 VL[4 * 1040];     // 8.125 KB (pad: d-stride 520 dw, %32==8)
    const int tid = threadIdx.x;
    const int h   = blockIdx.y;
    const int jc  = blockIdx.z;

    {   // stage Q chunk [1024][4] f16, linear
        const int4* Qg = (const int4*)(Qf + (size_t)(h * SL + jc * 1024) * 4);
        int4* QLv = (int4*)QL;
        #pragma unroll
        for (int u = 0; u < 2; ++u) QLv[tid + u * 256] = Qg[tid + u * 256];
        // stage Vp rows [4][1024] -> VL[d*1040 + j]
        #pragma unroll
        for (int u = 0; u < 2; ++u) {
            int t = tid + u * 256;
            int d = t >> 7, c = t & 127;
            *(int4*)&VL[d * 1040 + c * 8] =
                *(const int4*)(Vp + (size_t)(h * 4 + d) * SL + jc * 1024 + c * 8);
        }
    }
    __syncthreads();

    const int lane = tid & 63;
    const int wv   = __builtin_amdgcn_readfirstlane(tid >> 6);
    const int l16  = lane & 15;
    const int quad = lane >> 4;
    const int ib   = blockIdx.x * 64 + wv * 16;

    // B operand of score mfma: K i-tile, quads 1-3 zero
    half4 bk = (half4)(_Float16)0.f;
    if (lane < 16) bk = *(const half4*)(Kf + (size_t)(h * SL + ib + lane) * 4);

    const half4* QA = (const half4*)QL;            // index t*16 + l16
    const half4* VA = (const half4*)VL;            // index (l16&3)*260 + quad + t*4
    const int vbase = (l16 & 3) * 260 + quad;

    const f32x4 cz = {0.f, 0.f, 0.f, 0.f};
    f32x4 oacc = cz;

    #pragma unroll 4
    for (int t = 0; t < 64; ++t) {
        half4 aq = QA[t * 16 + l16];               // A[m=j][k=d]
        f32x4 s = __builtin_amdgcn_mfma_f32_16x16x16f16(aq, bk, cz, 0, 0, 0);
        // s: row j_local = t*16 + quad*4 + r, col i = l16
        fp16x2 p01 = __builtin_amdgcn_cvt_pkrtz(fexp2(s[0]), fexp2(s[1]));
        fp16x2 p23 = __builtin_amdgcn_cvt_pkrtz(fexp2(s[2]), fexp2(s[3]));
        half4 be = __builtin_bit_cast(half4,
                       __builtin_shufflevector(p01, p23, 0, 1, 2, 3));
        half4 av = VA[vbase + t * 4];              // A[m=d][k=j] (m>=4 dup/ignored)
        oacc = __builtin_amdgcn_mfma_f32_16x16x16f16(av, be, oacc, 0, 0, 0);
    }
    // O rows d=0..3 live in quad0: row = quad*4 + r
    if (lane < 16) {
        #pragma unroll
        for (int r = 0; r < 4; ++r)
            unsafeAtomicAdd(&AO[(size_t)(h * 4 + r) * SL + ib + lane], oacc[r]);
    }
}

// ---------------------------------------------------------------------------
// Kernel 4: output projection + bias + residual.
// ---------------------------------------------------------------------------
__global__ __launch_bounds__(256) void oproj_kernel(
    const float* __restrict__ AO, const float* __restrict__ Wo,
    const float* __restrict__ bo, const float* __restrict__ X,
    float* __restrict__ Y)
{
    const int lane = threadIdx.x & 63;
    const int wv   = __builtin_amdgcn_readfirstlane(threadIdx.x >> 6);
    const int l    = blockIdx.x * 64 + lane;
    const int cb   = blockIdx.y * 16 + wv * 4;

    float a0 = bo[cb + 0], a1 = bo[cb + 1], a2 = bo[cb + 2], a3 = bo[cb + 3];
    #pragma unroll 16
    for (int o = 0; o < 64; ++o) {
        float x = AO[o * SL + l];
        a0 = fmaf(Wo[(cb + 0) * 64 + o], x, a0);
        a1 = fmaf(Wo[(cb + 1) * 64 + o], x, a1);
        a2 = fmaf(Wo[(cb + 2) * 64 + o], x, a2);
        a3 = fmaf(Wo[(cb + 3) * 64 + o], x, a3);
    }
    Y[(cb + 0) * SL + l] = a0 + X[(cb + 0) * SL + l];
    Y[(cb + 1) * SL + l] = a1 + X[(cb + 1) * SL + l];
    Y[(cb + 2) * SL + l] = a2 + X[(cb + 2) * SL + l];
    Y[(cb + 3) * SL + l] = a3 + X[(cb + 3) * SL + l];
}

// ---------------------------------------------------------------------------
extern "C" void kernel_launch(void* const* d_in, const int* in_sizes, int n_in,
                              void* d_out, int out_size, void* d_ws, size_t ws_size,
                              hipStream_t stream)
{
    const float* X  = (const float*)d_in[0];
    const float* Wq = (const float*)d_in[1];
    const float* bq = (const float*)d_in[2];
    const float* Wk = (const float*)d_in[3];
    const float* bk = (const float*)d_in[4];
    const float* Wv = (const float*)d_in[5];
    const float* bv = (const float*)d_in[6];
    const float* Wo = (const float*)d_in[7];
    const float* bo = (const float*)d_in[8];
    float* Y = (float*)d_out;

    // workspace: 4 MB
    char* w = (char*)d_ws;
    _Float16* Qf = (_Float16*)(w);                  // [16][SL][4]   512 KB
    _Float16* Kf = (_Float16*)(w + (512 << 10));    // [16][SL][4]   512 KB
    _Float16* Vp = (_Float16*)(w + (1024 << 10));   // [16][4][SL]   512 KB
    float*    V4 = (float*)   (w + (1536 << 10));   // [16][SL][4]   1 MB
    float*    Zp = (float*)   (w + (2560 << 10));   // [2][16][SL]   512 KB
    float*    AO = (float*)   (w + (3072 << 10));   // [64][SL]      1 MB

    qkv_kernel<<<dim3(64, 4), 256, 0, stream>>>(X, Wq, bq, Wk, bk, Wv, bv,
                                                Qf, Kf, V4);
    zmfma_kernel<<<dim3(64, 16, 2), 256, 0, stream>>>(Qf, Kf, Zp);
    scalev_kernel<<<256, 256, 0, stream>>>(Zp, V4, Vp);
    (void)hipMemsetAsync(AO, 0, 64 * SL * sizeof(float), stream);
    omfma_kernel<<<dim3(64, 16, 4), 256, 0, stream>>>(Qf, Kf, Vp, AO);
    oproj_kernel<<<dim3(64, 16), 256, 0, stream>>>(AO, Wo, bo, X, Y);
}

// Round 5
// 147.036 us; speedup vs baseline: 1.8426x; 1.1888x over previous
//
#include <hip/hip_runtime.h>
#include <math.h>

// MultiheadSelfAttention2D: C=256, AC=64, HEADS=16, HEAD_DIM=4, L=4096.
// out[d,i] = sum_j exp(q_j.k_i) * (V[d,j]/Z_j), Z_j = sum_m exp(q_j.k_m).
// q,k unit vectors (L2-norm over d=4) => x = q.k in [-1,1].
//
// R5: Taylor linearization. exp(x) ~= T5(x) = sum_{n<=5} x^n/n!, max err
// e/720 ~ 1.6e-3 on [-1,1]. (q.k)^n/n! = sum_{|a|=n} (1/a!) q^a k^a, so
// E[j,i] = <phi(q_j), psi(k_i)> with phi_a = q^a/a!, psi_a = k^a over the
// 126 monomials of degree<=5 in 4 vars. Both passes become rank-126:
//   Z_j = phi(q_j).S,  S = sum_m psi(k_m)
//   out[d,i] = psi(k_i).M[:,d],  M[f,d] = sum_j phi_f(q_j) V[d,j]/Z_j
// All 537M exps eliminated; same stored f16 psi feeds S and out-pass, so
// normalization error cancels to first order.

constexpr int SL = 4096;
constexpr int NF = 126;     // #monomials deg<=5 in 4 vars

// ---------------------------------------------------------------------------
// Kernel 1: QKV projection + L2-norm. Qn/Kn/V4: [16][SL][4] fp32.
// Grid (64 l-tiles, 4 a-blocks), block 256; wave handles 12 output rows.
// ---------------------------------------------------------------------------
__global__ __launch_bounds__(256) void qkv_kernel(
    const float* __restrict__ X,
    const float* __restrict__ Wq, const float* __restrict__ bq,
    const float* __restrict__ Wk, const float* __restrict__ bk,
    const float* __restrict__ Wv, const float* __restrict__ bv,
    float* __restrict__ Qn, float* __restrict__ Kn, float* __restrict__ V4)
{
    __shared__ float XL[256 * 64];
    const int tid = threadIdx.x;
    const int lt  = blockIdx.x;
    const int ab  = blockIdx.y;

    const float4* Xg  = (const float4*)X;
    float4*       XL4 = (float4*)XL;
    #pragma unroll
    for (int i = 0; i < 16; ++i) {
        int idx = tid + i * 256;
        int c = idx >> 4, lq = idx & 15;
        XL4[c * 16 + lq] = Xg[c * (SL / 4) + lt * 16 + lq];
    }
    __syncthreads();

    const int lane   = tid & 63;
    const int wv     = __builtin_amdgcn_readfirstlane(tid >> 6);
    const int a_base = ab * 48 + wv * 12;
    const int l      = lt * 64 + lane;

    float acc[12];
    const float* wrow[12];
    #pragma unroll
    for (int k = 0; k < 12; ++k) {
        int a = a_base + k;
        if (a < 64)       { wrow[k] = Wq + a * 256;         acc[k] = bq[a]; }
        else if (a < 128) { wrow[k] = Wk + (a - 64) * 256;  acc[k] = bk[a - 64]; }
        else              { wrow[k] = Wv + (a - 128) * 256; acc[k] = bv[a - 128]; }
    }

    #pragma unroll 4
    for (int c = 0; c < 256; ++c) {
        float x = XL[c * 64 + lane];
        #pragma unroll
        for (int k = 0; k < 12; ++k) acc[k] = fmaf(wrow[k][c], x, acc[k]);
    }

    #pragma unroll
    for (int g = 0; g < 3; ++g) {
        int a0 = a_base + g * 4;
        float y0 = acc[g * 4 + 0], y1 = acc[g * 4 + 1];
        float y2 = acc[g * 4 + 2], y3 = acc[g * 4 + 3];
        int type = a0 >> 6;                 // 0=Q 1=K 2=V
        if (type < 2) {
            float n   = sqrtf(y0 * y0 + y1 * y1 + y2 * y2 + y3 * y3);
            float inv = 1.0f / fmaxf(n, 1e-12f);
            y0 *= inv; y1 *= inv; y2 *= inv; y3 *= inv;
        }
        int h = (a0 & 63) >> 2;
        float* base = (type == 0) ? Qn : (type == 1) ? Kn : V4;
        ((float4*)base)[h * SL + l] = make_float4(y0, y1, y2, y3);
    }
}

// ---------------------------------------------------------------------------
// Kernel 2: feature build. dst[h][f][pos] f16 = monomial (COEF: x 1/alpha!).
// Single enumeration loop used for both phi(q) and psi(k) => consistent
// feature ordering by construction. Grid (16, 16), block 256.
// ---------------------------------------------------------------------------
template <bool COEF>
__global__ __launch_bounds__(256) void feat_kernel(
    const float* __restrict__ src, _Float16* __restrict__ dst)
{
    const int pos = blockIdx.x * 256 + threadIdx.x;
    const int h   = blockIdx.y;
    float4 s = ((const float4*)src)[h * SL + pos];

    float p0[6], p1[6], p2[6], p3[6];
    p0[0] = p1[0] = p2[0] = p3[0] = 1.f;
    #pragma unroll
    for (int i = 1; i < 6; ++i) {
        p0[i] = p0[i - 1] * s.x; p1[i] = p1[i - 1] * s.y;
        p2[i] = p2[i - 1] * s.z; p3[i] = p3[i - 1] * s.w;
    }

    constexpr float INVF[6] = {1.f, 1.f, 0.5f, 1.f / 6.f, 1.f / 24.f, 1.f / 120.f};
    _Float16* out = dst + (size_t)h * NF * SL + pos;
    int f = 0;
    #pragma unroll
    for (int a = 0; a <= 5; ++a)
    #pragma unroll
    for (int b = 0; b <= 5 - a; ++b)
    #pragma unroll
    for (int c = 0; c <= 5 - a - b; ++c)
    #pragma unroll
    for (int d = 0; d <= 5 - a - b - c; ++d) {
        float val = (p0[a] * p1[b]) * (p2[c] * p3[d]);
        if (COEF) val *= (INVF[a] * INVF[b]) * (INVF[c] * INVF[d]);
        out[(size_t)f * SL] = (_Float16)val;
        ++f;
    }
}

// ---------------------------------------------------------------------------
// Kernel 3: S[h][f] = sum_m psi_f(k_m). Grid (126, 16), block 256.
// ---------------------------------------------------------------------------
__global__ __launch_bounds__(256) void ssum_kernel(
    const _Float16* __restrict__ Fk, float* __restrict__ Sv)
{
    const int f = blockIdx.x, h = blockIdx.y, tid = threadIdx.x;
    const _Float16* p = Fk + (size_t)(h * NF + f) * SL;
    float s = 0.f;
    #pragma unroll
    for (int u = 0; u < 16; ++u) s += (float)p[tid + u * 256];
    #pragma unroll
    for (int off = 32; off; off >>= 1) s += __shfl_down(s, off);
    __shared__ float ls[4];
    if ((tid & 63) == 0) ls[tid >> 6] = s;
    __syncthreads();
    if (tid == 0) Sv[h * NF + f] = (ls[0] + ls[1]) + (ls[2] + ls[3]);
}

// ---------------------------------------------------------------------------
// Kernel 4: Z_j = phi(q_j).S ; Vz[h][j][4] = V/Z. Grid (16, 16), block 256.
// ---------------------------------------------------------------------------
__global__ __launch_bounds__(256) void zvz_kernel(
    const _Float16* __restrict__ Fq, const float* __restrict__ Sv,
    const float* __restrict__ V4, float* __restrict__ Vz)
{
    const int j = blockIdx.x * 256 + threadIdx.x;
    const int h = blockIdx.y;
    const _Float16* p = Fq + (size_t)h * NF * SL + j;
    const float* Sh = Sv + h * NF;
    float z = 0.f;
    #pragma unroll 18
    for (int f = 0; f < NF; ++f) z = fmaf((float)p[(size_t)f * SL], Sh[f], z);
    float inv = 1.0f / z;                   // z >= 4096*0.36, never ~0
    float4 v = ((const float4*)V4)[h * SL + j];
    ((float4*)Vz)[h * SL + j] = make_float4(v.x * inv, v.y * inv, v.z * inv, v.w * inv);
}

// ---------------------------------------------------------------------------
// Kernel 5: M[h][f][d] = sum_j phi_f(q_j) * Vz[d,j]. Grid (126,16), block 256.
// ---------------------------------------------------------------------------
__global__ __launch_bounds__(256) void mmat_kernel(
    const _Float16* __restrict__ Fq, const float* __restrict__ Vz,
    float* __restrict__ Mm)
{
    const int f = blockIdx.x, h = blockIdx.y, tid = threadIdx.x;
    const _Float16* p = Fq + (size_t)(h * NF + f) * SL;
    const float4* v = (const float4*)Vz + h * SL;
    float a0 = 0.f, a1 = 0.f, a2 = 0.f, a3 = 0.f;
    #pragma unroll
    for (int u = 0; u < 16; ++u) {
        int j = tid + u * 256;
        float ph = (float)p[j];
        float4 vv = v[j];
        a0 = fmaf(ph, vv.x, a0); a1 = fmaf(ph, vv.y, a1);
        a2 = fmaf(ph, vv.z, a2); a3 = fmaf(ph, vv.w, a3);
    }
    #pragma unroll
    for (int off = 32; off; off >>= 1) {
        a0 += __shfl_down(a0, off); a1 += __shfl_down(a1, off);
        a2 += __shfl_down(a2, off); a3 += __shfl_down(a3, off);
    }
    __shared__ float ls[4][4];
    if ((tid & 63) == 0) {
        int wv = tid >> 6;
        ls[wv][0] = a0; ls[wv][1] = a1; ls[wv][2] = a2; ls[wv][3] = a3;
    }
    __syncthreads();
    if (tid == 0)
        ((float4*)Mm)[h * NF + f] = make_float4(
            (ls[0][0] + ls[1][0]) + (ls[2][0] + ls[3][0]),
            (ls[0][1] + ls[1][1]) + (ls[2][1] + ls[3][1]),
            (ls[0][2] + ls[1][2]) + (ls[2][2] + ls[3][2]),
            (ls[0][3] + ls[1][3]) + (ls[2][3] + ls[3][3]));
}

// ---------------------------------------------------------------------------
// Kernel 6: AO[h*4+d][i] += sum_{f in chunk} psi_f(k_i) * M[f][d].
// Grid (16, 16, 4 f-chunks of 32/32/32/30), block 256. M via s_load.
// ---------------------------------------------------------------------------
__global__ __launch_bounds__(256) void out_kernel(
    const _Float16* __restrict__ Fk, const float* __restrict__ Mm,
    float* __restrict__ AO)
{
    const int i = blockIdx.x * 256 + threadIdx.x;
    const int h = blockIdx.y;
    const int fbeg = blockIdx.z * 32;
    const int fend = (fbeg + 32 < NF) ? fbeg + 32 : NF;
    const _Float16* p = Fk + (size_t)h * NF * SL + i;
    const float4* Mh = (const float4*)Mm + h * NF;
    float a0 = 0.f, a1 = 0.f, a2 = 0.f, a3 = 0.f;
    #pragma unroll 8
    for (int f = fbeg; f < fend; ++f) {
        float ps = (float)p[(size_t)f * SL];
        float4 m = Mh[f];
        a0 = fmaf(ps, m.x, a0); a1 = fmaf(ps, m.y, a1);
        a2 = fmaf(ps, m.z, a2); a3 = fmaf(ps, m.w, a3);
    }
    unsafeAtomicAdd(&AO[(h * 4 + 0) * SL + i], a0);
    unsafeAtomicAdd(&AO[(h * 4 + 1) * SL + i], a1);
    unsafeAtomicAdd(&AO[(h * 4 + 2) * SL + i], a2);
    unsafeAtomicAdd(&AO[(h * 4 + 3) * SL + i], a3);
}

// ---------------------------------------------------------------------------
// Kernel 7: output projection + bias + residual.
// ---------------------------------------------------------------------------
__global__ __launch_bounds__(256) void oproj_kernel(
    const float* __restrict__ AO, const float* __restrict__ Wo,
    const float* __restrict__ bo, const float* __restrict__ X,
    float* __restrict__ Y)
{
    const int lane = threadIdx.x & 63;
    const int wv   = __builtin_amdgcn_readfirstlane(threadIdx.x >> 6);
    const int l    = blockIdx.x * 64 + lane;
    const int cb   = blockIdx.y * 16 + wv * 4;

    float a0 = bo[cb + 0], a1 = bo[cb + 1], a2 = bo[cb + 2], a3 = bo[cb + 3];
    #pragma unroll 16
    for (int o = 0; o < 64; ++o) {
        float x = AO[o * SL + l];
        a0 = fmaf(Wo[(cb + 0) * 64 + o], x, a0);
        a1 = fmaf(Wo[(cb + 1) * 64 + o], x, a1);
        a2 = fmaf(Wo[(cb + 2) * 64 + o], x, a2);
        a3 = fmaf(Wo[(cb + 3) * 64 + o], x, a3);
    }
    Y[(cb + 0) * SL + l] = a0 + X[(cb + 0) * SL + l];
    Y[(cb + 1) * SL + l] = a1 + X[(cb + 1) * SL + l];
    Y[(cb + 2) * SL + l] = a2 + X[(cb + 2) * SL + l];
    Y[(cb + 3) * SL + l] = a3 + X[(cb + 3) * SL + l];
}

// ---------------------------------------------------------------------------
extern "C" void kernel_launch(void* const* d_in, const int* in_sizes, int n_in,
                              void* d_out, int out_size, void* d_ws, size_t ws_size,
                              hipStream_t stream)
{
    const float* X  = (const float*)d_in[0];
    const float* Wq = (const float*)d_in[1];
    const float* bq = (const float*)d_in[2];
    const float* Wk = (const float*)d_in[3];
    const float* bk = (const float*)d_in[4];
    const float* Wv = (const float*)d_in[5];
    const float* bv = (const float*)d_in[6];
    const float* Wo = (const float*)d_in[7];
    const float* bo = (const float*)d_in[8];
    float* Y = (float*)d_out;

    // workspace (~41 MB)
    char* w = (char*)d_ws;
    float*    Qn = (float*)(w + (0 << 20));     // [16][SL][4] f32   1 MB
    float*    Kn = (float*)(w + (1 << 20));     // [16][SL][4] f32   1 MB
    float*    V4 = (float*)(w + (2 << 20));     // [16][SL][4] f32   1 MB
    float*    Vz = (float*)(w + (3 << 20));     // [16][SL][4] f32   1 MB
    float*    AO = (float*)(w + (4 << 20));     // [64][SL]    f32   1 MB
    float*    Mm = (float*)(w + (5 << 20));     // [16][126][4] f32  32 KB
    float*    Sv = (float*)(w + (5 << 20) + (1 << 16)); // [16][126] f32
    _Float16* Fq = (_Float16*)(w + (6 << 20));  // [16][126][SL] f16 16.5 MB
    _Float16* Fk = (_Float16*)(w + (24 << 20)); // [16][126][SL] f16 16.5 MB

    qkv_kernel<<<dim3(64, 4), 256, 0, stream>>>(X, Wq, bq, Wk, bk, Wv, bv,
                                                Qn, Kn, V4);
    feat_kernel<true ><<<dim3(16, 16), 256, 0, stream>>>(Qn, Fq);
    feat_kernel<false><<<dim3(16, 16), 256, 0, stream>>>(Kn, Fk);
    ssum_kernel<<<dim3(NF, 16), 256, 0, stream>>>(Fk, Sv);
    zvz_kernel<<<dim3(16, 16), 256, 0, stream>>>(Fq, Sv, V4, Vz);
    mmat_kernel<<<dim3(NF, 16), 256, 0, stream>>>(Fq, Vz, Mm);
    (void)hipMemsetAsync(AO, 0, 64 * SL * sizeof(float), stream);
    out_kernel<<<dim3(16, 16, 4), 256, 0, stream>>>(Fk, Mm, AO);
    oproj_kernel<<<dim3(64, 16), 256, 0, stream>>>(AO, Wo, bo, X, Y);
}